// Round 2
// baseline (15483.220 us; speedup 1.0000x reference)
//
#include <hip/hip_runtime.h>
#include <stdint.h>
#include <stddef.h>
#include <math.h>

// Problem constants
#define B_ 128
#define S_ 1024
#define I_ 512
#define H_ 1024
#define O_ 512

typedef __attribute__((ext_vector_type(4))) float f32x4;
typedef __attribute__((ext_vector_type(8))) short short8;
typedef __attribute__((ext_vector_type(2))) unsigned int uint2v;
typedef __attribute__((ext_vector_type(4))) unsigned int uint4v;

__device__ __forceinline__ unsigned short f2bf(float f) {
    unsigned u = __builtin_bit_cast(unsigned, f);
    u += 0x7fffu + ((u >> 16) & 1u);          // round-to-nearest-even
    return (unsigned short)(u >> 16);
}
__device__ __forceinline__ uint2v pack4(f32x4 v) {
    uint2v r;
    r.x = (unsigned)f2bf(v.x) | ((unsigned)f2bf(v.y) << 16);
    r.y = (unsigned)f2bf(v.z) | ((unsigned)f2bf(v.w) << 16);
    return r;
}

// ---------------- workspace layout (bytes) ----------------
// wfh  : W_hh bf16 frag-major              = 2097152
// wfi  : W_ih bf16 frag-major              = 1048576
// hbuf : [2][8 clusters][16384 els] bf16   =  524288
// cnt  : 8 x u32 barrier counters
#define OFF_WFI  2097152UL
#define OFF_HBUF 3145728UL
#define OFF_CNT  3670016UL
#define WS_NEED  (OFF_CNT + 64UL)

// ---------------- init: zero h0 and barrier counters ----------------
__global__ void rnn_init(unsigned int* hb32, unsigned int* cnt) {
    int idx = blockIdx.x * 256 + threadIdx.x;     // 65536 threads
    hb32[idx] = 0u;
    hb32[idx + 65536] = 0u;                       // 131072 u32 = 512 KB
    if (blockIdx.x == 0 && threadIdx.x < 8) cnt[threadIdx.x] = 0u;
}

// ---------------- W_hh fp32 -> bf16 frag-major ----------------
// el = ((wgn*2+t)*32 + kc)*512 + l*8 + j holds
//   Whh[n = 32*wgn + 16*t + (l&15)][k = 32*kc + 8*(l>>4) + j]
__global__ void rnn_convw_hh(const float* __restrict__ Whh,
                             unsigned short* __restrict__ wfh) {
    int G = blockIdx.x * 256 + threadIdx.x;       // 0..131071
    int l = G & 63, rest = G >> 6;
    int kc = rest & 31, t = (rest >> 5) & 1, wgn = rest >> 6;
    int n  = wgn * 32 + t * 16 + (l & 15);
    int k0 = kc * 32 + (l >> 4) * 8;
    const float* src = Whh + (size_t)n * H_ + k0;
    f32x4 f0 = *(const f32x4*)src, f1 = *(const f32x4*)(src + 4);
    uint2v a = pack4(f0), b = pack4(f1);
    uint4v pk; pk.x = a.x; pk.y = a.y; pk.z = b.x; pk.w = b.y;
    *(uint4v*)(wfh + (size_t)G * 8) = pk;
}

// ---------------- W_ih fp32 -> bf16 frag-major ----------------
// el = ((wgn*2+t)*16 + kc2)*512 + l*8 + j holds
//   Wih[n = 32*wgn + 16*t + (l&15)][k = 32*kc2 + 8*(l>>4) + j]
__global__ void rnn_convw_ih(const float* __restrict__ Wih,
                             unsigned short* __restrict__ wfi) {
    int G = blockIdx.x * 256 + threadIdx.x;       // 0..65535
    int l = G & 63, rest = G >> 6;
    int kc2 = rest & 15, t = (rest >> 4) & 1, wgn = rest >> 5;
    int n  = wgn * 32 + t * 16 + (l & 15);
    int k0 = kc2 * 32 + (l >> 4) * 8;
    const float* src = Wih + (size_t)n * I_ + k0;
    f32x4 f0 = *(const f32x4*)src, f1 = *(const f32x4*)(src + 4);
    uint2v a = pack4(f0), b = pack4(f1);
    uint4v pk; pk.x = a.x; pk.y = a.y; pk.z = b.x; pk.w = b.y;
    *(uint4v*)(wfi + (size_t)G * 8) = pk;
}

// ---------------- persistent fused recurrence ----------------
// 8 clusters (16 batch rows) x 32 WGs (32 hidden cols), cluster = bx&7 so a
// cluster's WGs share an XCD (round-robin heuristic; correctness-independent).
// Weights register-resident per wave; h double-buffered in global frag-major;
// per-cluster atomic barrier per step; x for step s+1 prefetched into regs.
__global__ __launch_bounds__(256, 1) void rnn_rec(
    const float* __restrict__ x,
    const unsigned short* __restrict__ wfh,
    const unsigned short* __restrict__ wfi,
    const float* __restrict__ bih, const float* __restrict__ bhh,
    unsigned short* __restrict__ hbuf,
    unsigned int* __restrict__ cnt)
{
    __shared__ unsigned short ldsH[16384];   // 32 KB h stage (frag-major)
    __shared__ unsigned short ldsX[8192];    // 16 KB x stage (frag-major)
    __shared__ float red[512];               //  2 KB cross-wave reduce

    int g = blockIdx.x & 7, wgn = blockIdx.x >> 3;
    int tid = threadIdx.x, l = tid & 63, w = tid >> 6;
    int t = w & 1, kk = w >> 1;              // ntile, K-half
    int li = l & 15, q = l >> 4;

    // B-fragments in registers (loop-invariant)
    short8 wh[16], wi[8];
    #pragma unroll
    for (int c = 0; c < 16; ++c)
        wh[c] = *(const short8*)(wfh +
            ((size_t)((wgn * 2 + t) * 32 + kk * 16 + c)) * 512 + l * 8);
    #pragma unroll
    for (int c = 0; c < 8; ++c)
        wi[c] = *(const short8*)(wfi +
            ((size_t)((wgn * 2 + t) * 16 + kk * 8 + c)) * 512 + l * 8);

    int hcol = wgn * 32 + t * 16 + li;       // output hidden col (kk==0 lanes)
    float bias = 0.f;
    if (kk == 0) bias = bih[hcol] + bhh[hcol];
    int q2 = (hcol >> 3) & 3, j2 = hcol & 7; // hcol>>5 == wgn
    unsigned short* houtB = hbuf + (size_t)g * 16384 + (size_t)wgn * 512 + j2;
    unsigned int* cg = cnt + g;

    // prefetch x for s=0: group G covers ldsX[G*8..G*8+8] =
    //   x[b = 16g + (G&15)][s][k = 32*(G>>6) + 8*((G&63)>>4) .. +8]
    f32x4 xr[8];
    #pragma unroll
    for (int i = 0; i < 4; ++i) {
        int G = tid + i * 256, l2 = G & 63, kc2 = G >> 6;
        const float* src = x + ((size_t)(g * 16 + (l2 & 15)) * S_ + 0) * I_
                             + kc2 * 32 + (l2 >> 4) * 8;
        xr[2 * i]     = *(const f32x4*)src;
        xr[2 * i + 1] = *(const f32x4*)(src + 4);
    }

    int bail = 0;
    #pragma unroll 1
    for (int s = 0; s < S_; ++s) {
        int cur = s & 1, nxt = cur ^ 1;
        // h stage: verbatim frag-major copy from hbuf[cur]
        const f32x4* hsrc = (const f32x4*)(hbuf + (size_t)cur * 131072
                                                + (size_t)g * 16384);
        f32x4 hr[8];
        #pragma unroll
        for (int i = 0; i < 8; ++i) hr[i] = hsrc[tid + i * 256];
        // x stage: pack prefetched regs -> LDS
        #pragma unroll
        for (int i = 0; i < 4; ++i) {
            int G = tid + i * 256;
            uint2v a = pack4(xr[2 * i]), b = pack4(xr[2 * i + 1]);
            uint4v pk; pk.x = a.x; pk.y = a.y; pk.z = b.x; pk.w = b.y;
            *(uint4v*)&ldsX[(size_t)G * 8] = pk;
        }
        #pragma unroll
        for (int i = 0; i < 8; ++i) ((f32x4*)ldsH)[tid + i * 256] = hr[i];
        __syncthreads();

        f32x4 acc = {0.f, 0.f, 0.f, 0.f}, acc2 = {0.f, 0.f, 0.f, 0.f};
        #pragma unroll
        for (int c = 0; c < 16; ++c) {
            short8 a = *(const short8*)&ldsH[(kk * 16 + c) * 512 + l * 8];
            acc = __builtin_amdgcn_mfma_f32_16x16x32_bf16(a, wh[c], acc, 0, 0, 0);
        }
        #pragma unroll
        for (int c = 0; c < 8; ++c) {
            short8 a = *(const short8*)&ldsX[(kk * 8 + c) * 512 + l * 8];
            acc2 = __builtin_amdgcn_mfma_f32_16x16x32_bf16(a, wi[c], acc2, 0, 0, 0);
        }
        acc += acc2;

        // prefetch next x (latency hides behind reduce + barrier)
        int sp = (s + 1 < S_) ? s + 1 : 0;
        #pragma unroll
        for (int i = 0; i < 4; ++i) {
            int G = tid + i * 256, l2 = G & 63, kc2 = G >> 6;
            const float* src = x + ((size_t)(g * 16 + (l2 & 15)) * S_ + sp) * I_
                                 + kc2 * 32 + (l2 >> 4) * 8;
            xr[2 * i]     = *(const f32x4*)src;
            xr[2 * i + 1] = *(const f32x4*)(src + 4);
        }

        if (kk == 1) *(f32x4*)&red[t * 256 + l * 4] = acc;
        __syncthreads();
        if (kk == 0) {
            f32x4 p = *(const f32x4*)&red[t * 256 + l * 4];
            unsigned short* hout = houtB + (size_t)nxt * 131072;
            #pragma unroll
            for (int i = 0; i < 4; ++i) {
                float v = tanhf(acc[i] + p[i] + bias);
                hout[(q2 * 16 + q * 4 + i) * 8] = f2bf(v);
            }
        }
        __syncthreads();   // drains h stores (vmcnt) before arrival
        if (tid == 0) {
            __hip_atomic_fetch_add(cg, 1u, __ATOMIC_RELEASE,
                                   __HIP_MEMORY_SCOPE_AGENT);
            if (!bail) {
                unsigned target = 32u * (unsigned)(s + 1);
                int polls = 0;
                while (__hip_atomic_load(cg, __ATOMIC_RELAXED,
                                         __HIP_MEMORY_SCOPE_AGENT) < target) {
                    __builtin_amdgcn_s_sleep(2);
                    if (++polls > (1 << 22)) { bail = 1; break; }  // anti-hang
                }
                __threadfence();   // acquire: invalidate stale caches
            }
        }
        __syncthreads();
    }
}

// ---------------- out = hT @ W_fc^T + b_fc ----------------
__global__ __launch_bounds__(256) void rnn_fc(
    const unsigned short* __restrict__ hb0,
    const float* __restrict__ Wfc, const float* __restrict__ bfc,
    float* __restrict__ out)
{
    __shared__ unsigned short ldsB[8 * 64 * 8];   // 8 KB
    int n_blk = blockIdx.x;                       // 4 blocks of 128 o-cols
    int tid = threadIdx.x, l = tid & 63, w = tid >> 6;
    int li = l & 15, q = l >> 4;
    f32x4 acc[8][2];
    f32x4 z = {0.f, 0.f, 0.f, 0.f};
    #pragma unroll
    for (int mb = 0; mb < 8; ++mb) { acc[mb][0] = z; acc[mb][1] = z; }

    for (int kc = 0; kc < 32; ++kc) {
        #pragma unroll
        for (int u = 0; u < 2; ++u) {
            int G = tid * 2 + u;
            int nt = G >> 6, ll = G & 63;
            int n = n_blk * 128 + nt * 16 + (ll & 15);
            int k = kc * 32 + (ll >> 4) * 8;
            const float* src = Wfc + (size_t)n * H_ + k;
            f32x4 f0 = *(const f32x4*)src, f1 = *(const f32x4*)(src + 4);
            uint2v a = pack4(f0), b = pack4(f1);
            uint4v pk; pk.x = a.x; pk.y = a.y; pk.z = b.x; pk.w = b.y;
            *(uint4v*)&ldsB[G * 8] = pk;
        }
        __syncthreads();
        short8 bfr[2];
        #pragma unroll
        for (int tn = 0; tn < 2; ++tn)
            bfr[tn] = *(const short8*)&ldsB[((w * 2 + tn) * 64 + l) * 8];
        #pragma unroll
        for (int mb = 0; mb < 8; ++mb) {
            short8 a = *(const short8*)(hb0 + (size_t)mb * 16384 + kc * 512 + l * 8);
            acc[mb][0] = __builtin_amdgcn_mfma_f32_16x16x32_bf16(a, bfr[0], acc[mb][0], 0, 0, 0);
            acc[mb][1] = __builtin_amdgcn_mfma_f32_16x16x32_bf16(a, bfr[1], acc[mb][1], 0, 0, 0);
        }
        __syncthreads();
    }
    #pragma unroll
    for (int mb = 0; mb < 8; ++mb)
        #pragma unroll
        for (int tn = 0; tn < 2; ++tn)
            #pragma unroll
            for (int i = 0; i < 4; ++i) {
                int b = mb * 16 + q * 4 + i;
                int o = n_blk * 128 + (w * 2 + tn) * 16 + li;
                out[(size_t)b * O_ + o] = acc[mb][tn][i] + bfc[o];
            }
}

extern "C" void kernel_launch(void* const* d_in, const int* in_sizes, int n_in,
                              void* d_out, int out_size, void* d_ws, size_t ws_size,
                              hipStream_t stream) {
    const float* x   = (const float*)d_in[0];
    const float* Wih = (const float*)d_in[1];
    const float* Whh = (const float*)d_in[2];
    const float* bih = (const float*)d_in[3];
    const float* bhh = (const float*)d_in[4];
    const float* Wfc = (const float*)d_in[5];
    const float* bfc = (const float*)d_in[6];
    float* out = (float*)d_out;
    (void)in_sizes; (void)n_in; (void)out_size;

    if (ws_size < WS_NEED) return;   // fail visibly (absmax), never fault

    char* ws = (char*)d_ws;
    unsigned short* wfh  = (unsigned short*)ws;
    unsigned short* wfi  = (unsigned short*)(ws + OFF_WFI);
    unsigned short* hbuf = (unsigned short*)(ws + OFF_HBUF);
    unsigned int*   cnt  = (unsigned int*)(ws + OFF_CNT);

    rnn_init<<<256, 256, 0, stream>>>((unsigned int*)hbuf, cnt);
    rnn_convw_hh<<<512, 256, 0, stream>>>(Whh, wfh);
    rnn_convw_ih<<<256, 256, 0, stream>>>(Wih, wfi);

    const float* xa = x; const float* biha = bih; const float* bhha = bhh;
    void* args[] = {(void*)&xa, (void*)&wfh, (void*)&wfi,
                    (void*)&biha, (void*)&bhha, (void*)&hbuf, (void*)&cnt};
    hipLaunchCooperativeKernel((const void*)rnn_rec, dim3(256), dim3(256),
                               args, 0, stream);

    rnn_fc<<<4, 256, 0, stream>>>(hbuf, Wfc, bfc, out);
}

// Round 3
// 5673.055 us; speedup vs baseline: 2.7293x; 2.7293x over previous
//
#include <hip/hip_runtime.h>
#include <stdint.h>
#include <stddef.h>
#include <math.h>

// Problem constants
#define B_ 128
#define S_ 1024
#define I_ 512
#define H_ 1024
#define O_ 512

typedef __attribute__((ext_vector_type(4))) float f32x4;
typedef __attribute__((ext_vector_type(8))) short short8;
typedef __attribute__((ext_vector_type(2))) unsigned int uint2v;
typedef __attribute__((ext_vector_type(4))) unsigned int uint4v;

__device__ __forceinline__ unsigned short f2bf(float f) {
    unsigned u = __builtin_bit_cast(unsigned, f);
    u += 0x7fffu + ((u >> 16) & 1u);          // round-to-nearest-even
    return (unsigned short)(u >> 16);
}
__device__ __forceinline__ uint2v pack4(f32x4 v) {
    uint2v r;
    r.x = (unsigned)f2bf(v.x) | ((unsigned)f2bf(v.y) << 16);
    r.y = (unsigned)f2bf(v.z) | ((unsigned)f2bf(v.w) << 16);
    return r;
}
// Device-coherent (agent-scope, relaxed) accesses: lower to sc1-flagged
// global ops — per-access coherence, NO buffer_wbl2 / buffer_inv storms.
__device__ __forceinline__ unsigned long long ld_u64_coh(const unsigned long long* p) {
    return __hip_atomic_load(p, __ATOMIC_RELAXED, __HIP_MEMORY_SCOPE_AGENT);
}
__device__ __forceinline__ void st_u32_coh(unsigned int* p, unsigned int v) {
    __hip_atomic_store(p, v, __ATOMIC_RELAXED, __HIP_MEMORY_SCOPE_AGENT);
}

// ---------------- workspace layout (bytes) ----------------
// wfh  : W_hh bf16 frag-major              = 2097152
// wfi  : W_ih bf16 frag-major              = 1048576
// hbuf : [2][8 clusters][16384 els] bf16   =  524288
// cnt  : 8 x u32 barrier counters
#define OFF_WFI  2097152UL
#define OFF_HBUF 3145728UL
#define OFF_CNT  3670016UL
#define WS_NEED  (OFF_CNT + 64UL)

// ---------------- init: zero h0 and barrier counters ----------------
__global__ void rnn_init(unsigned int* hb32, unsigned int* cnt) {
    int idx = blockIdx.x * 256 + threadIdx.x;     // 65536 threads
    hb32[idx] = 0u;
    hb32[idx + 65536] = 0u;                       // 131072 u32 = 512 KB
    if (blockIdx.x == 0 && threadIdx.x < 8) cnt[threadIdx.x] = 0u;
}

// ---------------- W_hh fp32 -> bf16 frag-major ----------------
// el = ((wgn*2+t)*32 + kc)*512 + l*8 + j holds
//   Whh[n = 32*wgn + 16*t + (l&15)][k = 32*kc + 8*(l>>4) + j]
__global__ void rnn_convw_hh(const float* __restrict__ Whh,
                             unsigned short* __restrict__ wfh) {
    int G = blockIdx.x * 256 + threadIdx.x;       // 0..131071
    int l = G & 63, rest = G >> 6;
    int kc = rest & 31, t = (rest >> 5) & 1, wgn = rest >> 6;
    int n  = wgn * 32 + t * 16 + (l & 15);
    int k0 = kc * 32 + (l >> 4) * 8;
    const float* src = Whh + (size_t)n * H_ + k0;
    f32x4 f0 = *(const f32x4*)src, f1 = *(const f32x4*)(src + 4);
    uint2v a = pack4(f0), b = pack4(f1);
    uint4v pk; pk.x = a.x; pk.y = a.y; pk.z = b.x; pk.w = b.y;
    *(uint4v*)(wfh + (size_t)G * 8) = pk;
}

// ---------------- W_ih fp32 -> bf16 frag-major ----------------
__global__ void rnn_convw_ih(const float* __restrict__ Wih,
                             unsigned short* __restrict__ wfi) {
    int G = blockIdx.x * 256 + threadIdx.x;       // 0..65535
    int l = G & 63, rest = G >> 6;
    int kc2 = rest & 15, t = (rest >> 4) & 1, wgn = rest >> 5;
    int n  = wgn * 32 + t * 16 + (l & 15);
    int k0 = kc2 * 32 + (l >> 4) * 8;
    const float* src = Wih + (size_t)n * I_ + k0;
    f32x4 f0 = *(const f32x4*)src, f1 = *(const f32x4*)(src + 4);
    uint2v a = pack4(f0), b = pack4(f1);
    uint4v pk; pk.x = a.x; pk.y = a.y; pk.z = b.x; pk.w = b.y;
    *(uint4v*)(wfi + (size_t)G * 8) = pk;
}

// ---------------- persistent fused recurrence ----------------
// 8 clusters (16 batch rows) x 32 WGs (32 hidden cols). Weights
// register/AGPR-resident; h double-buffered in global frag-major and
// exchanged via per-access device-coherent (sc1) atomics — no cache-wide
// wbl2/inv. Per-cluster relaxed atomic counter barrier per step.
__global__ __launch_bounds__(256, 1) void rnn_rec(
    const float* __restrict__ x,
    const unsigned short* __restrict__ wfh,
    const unsigned short* __restrict__ wfi,
    const float* __restrict__ bih, const float* __restrict__ bhh,
    unsigned short* __restrict__ hbuf,
    unsigned int* __restrict__ cnt)
{
    __shared__ unsigned short ldsH[16384];   // 32 KB h stage (frag-major)
    __shared__ unsigned short ldsX[8192];    // 16 KB x stage (frag-major)
    __shared__ float red[512];               //  2 KB cross-wave reduce

    int g = blockIdx.x & 7, wgn = blockIdx.x >> 3;
    int tid = threadIdx.x, l = tid & 63, w = tid >> 6;
    int t = w & 1, kk = w >> 1;              // ntile, K-half
    int li = l & 15, q = l >> 4;

    // B-fragments resident (loop-invariant)
    short8 wh[16], wi[8];
    #pragma unroll
    for (int c = 0; c < 16; ++c)
        wh[c] = *(const short8*)(wfh +
            ((size_t)((wgn * 2 + t) * 32 + kk * 16 + c)) * 512 + l * 8);
    #pragma unroll
    for (int c = 0; c < 8; ++c)
        wi[c] = *(const short8*)(wfi +
            ((size_t)((wgn * 2 + t) * 16 + kk * 8 + c)) * 512 + l * 8);

    int hcol = wgn * 32 + t * 16 + li;       // output hidden col (kk==0 lanes)
    float bias = 0.f;
    if (kk == 0) bias = bih[hcol] + bhh[hcol];
    int q2 = (hcol >> 3) & 3, j2 = hcol & 7; // hcol>>5 == wgn
    unsigned int* cg = cnt + g;

    // prefetch x for s=0 and pack into ldsX:
    //   group G covers ldsX[G*8..+8] = x[b=16g+(G&15)][s][32*(G>>6)+8*((G&63)>>4)..+8]
    f32x4 xr[8];
    #pragma unroll
    for (int i = 0; i < 4; ++i) {
        int G = tid + i * 256, l2 = G & 63, kc2 = G >> 6;
        const float* src = x + ((size_t)(g * 16 + (l2 & 15)) * S_ + 0) * I_
                             + kc2 * 32 + (l2 >> 4) * 8;
        xr[2 * i]     = *(const f32x4*)src;
        xr[2 * i + 1] = *(const f32x4*)(src + 4);
    }
    #pragma unroll
    for (int i = 0; i < 4; ++i) {
        int G = tid + i * 256;
        uint2v a = pack4(xr[2 * i]), b = pack4(xr[2 * i + 1]);
        uint4v pk; pk.x = a.x; pk.y = a.y; pk.z = b.x; pk.w = b.y;
        *(uint4v*)&ldsX[(size_t)G * 8] = pk;
    }

    int bail = 0;
    #pragma unroll 1
    for (int s = 0; s < S_; ++s) {
        int cur = s & 1, nxt = cur ^ 1;
        // h stage: coherent u64 loads (verbatim frag-major copy) -> LDS
        const unsigned long long* hsrc = (const unsigned long long*)hbuf
            + (size_t)cur * 32768 + (size_t)g * 4096;
        unsigned long long hr[16];
        #pragma unroll
        for (int u = 0; u < 8; ++u) {
            hr[2 * u]     = ld_u64_coh(hsrc + (size_t)u * 512 + tid * 2);
            hr[2 * u + 1] = ld_u64_coh(hsrc + (size_t)u * 512 + tid * 2 + 1);
        }
        #pragma unroll
        for (int u = 0; u < 8; ++u) {
            ((unsigned long long*)ldsH)[u * 512 + tid * 2]     = hr[2 * u];
            ((unsigned long long*)ldsH)[u * 512 + tid * 2 + 1] = hr[2 * u + 1];
        }
        __syncthreads();                               // (A) stage ready

        f32x4 acc = {0.f, 0.f, 0.f, 0.f}, acc2 = {0.f, 0.f, 0.f, 0.f};
        #pragma unroll
        for (int c = 0; c < 16; ++c) {
            short8 a = *(const short8*)&ldsH[(kk * 16 + c) * 512 + l * 8];
            acc = __builtin_amdgcn_mfma_f32_16x16x32_bf16(a, wh[c], acc, 0, 0, 0);
        }
        #pragma unroll
        for (int c = 0; c < 8; ++c) {
            short8 a = *(const short8*)&ldsX[(kk * 8 + c) * 512 + l * 8];
            acc2 = __builtin_amdgcn_mfma_f32_16x16x32_bf16(a, wi[c], acc2, 0, 0, 0);
        }
        acc += acc2;

        // prefetch next x (plain cached loads; overlaps reduce+store+spin)
        int sp = (s + 1 < S_) ? s + 1 : 0;
        #pragma unroll
        for (int i = 0; i < 4; ++i) {
            int G = tid + i * 256, l2 = G & 63, kc2 = G >> 6;
            const float* src = x + ((size_t)(g * 16 + (l2 & 15)) * S_ + sp) * I_
                                 + kc2 * 32 + (l2 >> 4) * 8;
            xr[2 * i]     = *(const f32x4*)src;
            xr[2 * i + 1] = *(const f32x4*)(src + 4);
        }

        if (kk == 1) *(f32x4*)&red[t * 256 + l * 4] = acc;
        __syncthreads();                               // (B) red ready, LDS reads done
        if (kk == 0) {
            f32x4 p = *(const f32x4*)&red[t * 256 + l * 4];
            unsigned int* hout32 = (unsigned int*)(hbuf
                + (size_t)nxt * 131072 + (size_t)g * 16384
                + (size_t)wgn * 512 + j2);             // 4B-aligned on even lanes
            #pragma unroll
            for (int i = 0; i < 4; ++i) {
                float v = tanhf(acc[i] + p[i] + bias);
                unsigned short mybf = f2bf(v);
                unsigned nb = (unsigned)__shfl_xor((int)mybf, 1, 64) & 0xffffu;
                if ((li & 1) == 0) {
                    unsigned word = (unsigned)mybf | (nb << 16);
                    st_u32_coh(hout32 + (q2 * 16 + q * 4 + i) * 4, word);
                }
            }
        }
        // pack prefetched x for s+1 (overlaps the barrier spin)
        #pragma unroll
        for (int i = 0; i < 4; ++i) {
            int G = tid + i * 256;
            uint2v a = pack4(xr[2 * i]), b = pack4(xr[2 * i + 1]);
            uint4v pk; pk.x = a.x; pk.y = a.y; pk.z = b.x; pk.w = b.y;
            *(uint4v*)&ldsX[(size_t)G * 8] = pk;
        }
        __syncthreads();   // (C) h stores drained (vmcnt0 before s_barrier)
        if (tid == 0) {
            __hip_atomic_fetch_add(cg, 1u, __ATOMIC_RELAXED,
                                   __HIP_MEMORY_SCOPE_AGENT);
            if (!bail) {
                unsigned target = 32u * (unsigned)(s + 1);
                int polls = 0;
                while (__hip_atomic_load(cg, __ATOMIC_RELAXED,
                                         __HIP_MEMORY_SCOPE_AGENT) < target) {
                    __builtin_amdgcn_s_sleep(1);
                    if (++polls > (1 << 24)) { bail = 1; break; }  // anti-hang
                }
            }
        }
        __syncthreads();                               // (D) step barrier passed
    }
}

// ---------------- out = hT @ W_fc^T + b_fc ----------------
__global__ __launch_bounds__(256) void rnn_fc(
    const unsigned short* __restrict__ hb0,
    const float* __restrict__ Wfc, const float* __restrict__ bfc,
    float* __restrict__ out)
{
    __shared__ unsigned short ldsB[8 * 64 * 8];   // 8 KB
    int n_blk = blockIdx.x;                       // 4 blocks of 128 o-cols
    int tid = threadIdx.x, l = tid & 63, w = tid >> 6;
    int li = l & 15, q = l >> 4;
    f32x4 acc[8][2];
    f32x4 z = {0.f, 0.f, 0.f, 0.f};
    #pragma unroll
    for (int mb = 0; mb < 8; ++mb) { acc[mb][0] = z; acc[mb][1] = z; }

    for (int kc = 0; kc < 32; ++kc) {
        #pragma unroll
        for (int u = 0; u < 2; ++u) {
            int G = tid * 2 + u;
            int nt = G >> 6, ll = G & 63;
            int n = n_blk * 128 + nt * 16 + (ll & 15);
            int k = kc * 32 + (ll >> 4) * 8;
            const float* src = Wfc + (size_t)n * H_ + k;
            f32x4 f0 = *(const f32x4*)src, f1 = *(const f32x4*)(src + 4);
            uint2v a = pack4(f0), b = pack4(f1);
            uint4v pk; pk.x = a.x; pk.y = a.y; pk.z = b.x; pk.w = b.y;
            *(uint4v*)&ldsB[G * 8] = pk;
        }
        __syncthreads();
        short8 bfr[2];
        #pragma unroll
        for (int tn = 0; tn < 2; ++tn)
            bfr[tn] = *(const short8*)&ldsB[((w * 2 + tn) * 64 + l) * 8];
        #pragma unroll
        for (int mb = 0; mb < 8; ++mb) {
            short8 a = *(const short8*)(hb0 + (size_t)mb * 16384 + kc * 512 + l * 8);
            acc[mb][0] = __builtin_amdgcn_mfma_f32_16x16x32_bf16(a, bfr[0], acc[mb][0], 0, 0, 0);
            acc[mb][1] = __builtin_amdgcn_mfma_f32_16x16x32_bf16(a, bfr[1], acc[mb][1], 0, 0, 0);
        }
        __syncthreads();
    }
    #pragma unroll
    for (int mb = 0; mb < 8; ++mb)
        #pragma unroll
        for (int tn = 0; tn < 2; ++tn)
            #pragma unroll
            for (int i = 0; i < 4; ++i) {
                int b = mb * 16 + q * 4 + i;
                int o = n_blk * 128 + (w * 2 + tn) * 16 + li;
                out[(size_t)b * O_ + o] = acc[mb][tn][i] + bfc[o];
            }
}

extern "C" void kernel_launch(void* const* d_in, const int* in_sizes, int n_in,
                              void* d_out, int out_size, void* d_ws, size_t ws_size,
                              hipStream_t stream) {
    const float* x   = (const float*)d_in[0];
    const float* Wih = (const float*)d_in[1];
    const float* Whh = (const float*)d_in[2];
    const float* bih = (const float*)d_in[3];
    const float* bhh = (const float*)d_in[4];
    const float* Wfc = (const float*)d_in[5];
    const float* bfc = (const float*)d_in[6];
    float* out = (float*)d_out;
    (void)in_sizes; (void)n_in; (void)out_size;

    if (ws_size < WS_NEED) return;   // fail visibly (absmax), never fault

    char* ws = (char*)d_ws;
    unsigned short* wfh  = (unsigned short*)ws;
    unsigned short* wfi  = (unsigned short*)(ws + OFF_WFI);
    unsigned short* hbuf = (unsigned short*)(ws + OFF_HBUF);
    unsigned int*   cnt  = (unsigned int*)(ws + OFF_CNT);

    rnn_init<<<256, 256, 0, stream>>>((unsigned int*)hbuf, cnt);
    rnn_convw_hh<<<512, 256, 0, stream>>>(Whh, wfh);
    rnn_convw_ih<<<256, 256, 0, stream>>>(Wih, wfi);

    const float* xa = x; const float* biha = bih; const float* bhha = bhh;
    void* args[] = {(void*)&xa, (void*)&wfh, (void*)&wfi,
                    (void*)&biha, (void*)&bhha, (void*)&hbuf, (void*)&cnt};
    hipLaunchCooperativeKernel((const void*)rnn_rec, dim3(256), dim3(256),
                               args, 0, stream);

    rnn_fc<<<4, 256, 0, stream>>>(hbuf, Wfc, bfc, out);
}